// Round 11
// baseline (1479.841 us; speedup 1.0000x reference)
//
#include <hip/hip_runtime.h>

// HMM forward (CgpHmmCell): B=512, T=4096, S=64, M=125.
// Round 11: (1) early-exit extract — probe each row 64 B (16 dwords) at a
// time, per-thread, stop at the one-hot hit. pos~U{0..124} => E[64B chunks]
// = 4.42 (~5.4 device lines with the 500-B-row misalignment) => ~347 B/row
// vs 500: FETCH 1.07 GB -> ~0.73 GB, extract ~190 -> ~120 us. Scalar loads
// (rows are only 4-B aligned); 16 independent loads per probe keep the
// vmcnt queue full; done lanes are exec-masked and fetch nothing.
// (2) scan register slimming: E-loads moved inside the per-chain loop
// (R10 hoisted E for all 4 chains = 64 VGPRs live -> chains serialized).
// Scan algorithm unchanged from R10 (absmax 0.0): permuted-K contraction
// (zero-shuffle C->B: pi(32kf+8g+2j2+e)=32kf+16(j2>>1)+4g+2(j2&1)+e absorbed
// into Af), 128 chunks/seq x 32 steps, burn 16, mass identity dL = S1-S0,
// chunk-0 exact I*E0 override, 4 chains x 16 streams per wave, one
// atomicAdd per wave.

#define BATCH 512
#define T 4096
#define S 64
#define M 125
#define CHUNKP 4   // packs per chunk (32 steps)
#define BURNP 2    // burn packs (16 steps)
#define NPACK 6
#define WPB 4
#define NQ 4       // independent chains per wave

typedef __attribute__((ext_vector_type(8))) short bf16x8;
typedef __attribute__((ext_vector_type(4))) float f32x4;

union BFU { unsigned u[4]; bf16x8 v; };

__device__ __forceinline__ unsigned pk_trunc(float a, float b) {
    return (__float_as_uint(b) & 0xFFFF0000u) | (__float_as_uint(a) >> 16);
}
__device__ __forceinline__ unsigned pk_rne(float a, float b) {
    unsigned ua = __float_as_uint(a); ua += 0x7FFFu + ((ua >> 16) & 1u);
    unsigned ub = __float_as_uint(b); ub += 0x7FFFu + ((ub >> 16) & 1u);
    return (ub & 0xFFFF0000u) | (ua >> 16);
}

// ------------- Phase 1: early-exit one-hot index probe (per thread) --------
__global__ __launch_bounds__(256) void extract_obs(const float* __restrict__ x,
                                                   unsigned char* __restrict__ obs) {
    const long long row = (long long)blockIdx.x * 256 + threadIdx.x;
    const float* r = x + row * (long long)M;
    int o = 0;
#pragma unroll 1
    for (int j = 0; j < 8; ++j) {
        const int base = j * 16;
        const int n = (j < 7) ? 16 : (M - 112);   // 16, last chunk 13
        float v[16];
#pragma unroll
        for (int t = 0; t < 16; ++t)
            v[t] = (t < n) ? r[base + t] : 0.0f;  // n is compile-time per j
        int found = -1;
#pragma unroll
        for (int t = 0; t < 16; ++t)
            if (v[t] != 0.0f) found = base + t;
        if (found >= 0) { o = found; break; }
    }
    obs[row] = (unsigned char)o;
}

// ---------------- Phase 2: MFMA scan, 4 chains x 16 streams per wave --------
__global__ __launch_bounds__(256) void hmm_mfma(const unsigned char* __restrict__ obs,
                                                const float* __restrict__ Iv,
                                                const float* __restrict__ A,
                                                const float* __restrict__ Bm,
                                                float* __restrict__ out) {
    __shared__ __align__(16) float BmL[M * S];        // 32000 B
    __shared__ __align__(16) float ILds[S];

    const int tid = threadIdx.x, lane = tid & 63;
    const int s = lane & 15, g = lane >> 4;

    for (int i = tid; i < M * S; i += WPB * 64) BmL[i] = Bm[i];
    if (tid < S) ILds[tid] = Iv[tid];
    __syncthreads();

    // A^T fragments under pi: slot (kf,g,j2,e) holds A[p0+e][16mt+s],
    // p0 = 32kf + 16*(j2>>1) + 4g + 2*(j2&1).
    BFU Af[4][2];
#pragma unroll
    for (int mt = 0; mt < 4; ++mt)
#pragma unroll
        for (int kf = 0; kf < 2; ++kf)
#pragma unroll
            for (int j2 = 0; j2 < 4; ++j2) {
                int p0 = 32 * kf + 16 * (j2 >> 1) + 4 * g + 2 * (j2 & 1);
                Af[mt][kf].u[j2] = pk_rne(A[(size_t)p0 * S + mt * 16 + s],
                                          A[(size_t)(p0 + 1) * S + mt * 16 + s]);
            }

    const int W = blockIdx.x * WPB + (tid >> 6);  // 0..1023
    const int seq = W >> 1, half = W & 1;         // 2 waves per sequence
    const unsigned long long* orow = (const unsigned long long*)(obs + (size_t)seq * T);
    const int adrC = s << 2;                      // bpermute: pull lane s (g=0)

    int idx0[NQ];
    unsigned long long u[NQ], un[NQ];
    BFU Bf[NQ][2];
    float Ls[NQ], S0v[NQ], cc[NQ], swv[NQ];
#pragma unroll
    for (int q = 0; q < NQ; ++q) {
        int chunk = half * 64 + q * 16 + s;       // this lane/chain's stream
        idx0[q] = chunk * CHUNKP - BURNP;
        u[q] = orow[idx0[q] < 0 ? 0 : idx0[q]];
        Ls[q] = 0.f; S0v[q] = 0.f; cc[q] = 1.f; swv[q] = 1.f;
#pragma unroll
        for (int kf = 0; kf < 2; ++kf)
#pragma unroll
            for (int j = 0; j < 4; ++j) Bf[q][kf].u[j] = 0x3F803F80u;  // 1.0 seed
    }

    for (int p = 0; p < NPACK; ++p) {
#pragma unroll
        for (int q = 0; q < NQ; ++q) {
            int in_ = idx0[q] + p + 1;
            in_ = in_ < 0 ? 0 : (in_ > T / 8 - 1 ? T / 8 - 1 : in_);
            un[q] = orow[in_];                    // prefetch next pack
        }
        const bool ovp = (half == 0) && (p == BURNP);
#pragma unroll
        for (int k = 0; k < 8; ++k) {
#pragma unroll
            for (int q = 0; q < NQ; ++q) {
                const int o = (int)((u[q] >> (8 * k)) & 255ull);
                const float* br = &BmL[o << 6];   // wave-uniform -> broadcast reads
                f32x4 E[4];
#pragma unroll
                for (int mt = 0; mt < 4; ++mt)
                    E[mt] = *(const f32x4*)&br[mt * 16 + g * 4];
                float w[4][4];
#pragma unroll
                for (int mt = 0; mt < 4; ++mt) {
                    f32x4 z = {0.f, 0.f, 0.f, 0.f};
                    z = __builtin_amdgcn_mfma_f32_16x16x32_bf16(Af[mt][0].v, Bf[q][0].v, z, 0, 0, 0);
                    z = __builtin_amdgcn_mfma_f32_16x16x32_bf16(Af[mt][1].v, Bf[q][1].v, z, 0, 0, 0);
#pragma unroll
                    for (int r = 0; r < 4; ++r) w[mt][r] = z[r] * E[mt][r];
                }
                if (ovp && k == 0 && q == 0) {    // exact t=0 init of chunk 0
                    const bool c0 = (s == 0);
#pragma unroll
                    for (int mt = 0; mt < 4; ++mt)
#pragma unroll
                        for (int r = 0; r < 4; ++r)
                            w[mt][r] = c0 ? ILds[mt * 16 + g * 4 + r] * E[mt][r] : w[mt][r];
                }
                float scale = 1.f;
                if (k == 7) {                     // per-pack surrogate rescale
                    float swl = 0.f;
#pragma unroll
                    for (int mt = 0; mt < 4; ++mt)
#pragma unroll
                        for (int r = 0; r < 4; ++r) swl += w[mt][r];
                    swl += __shfl_xor(swl, 16);
                    swl += __shfl_xor(swl, 32);
                    swv[q] = swl;                 // pre-scale mass (boundary/final)
                    float c = __uint_as_float(__builtin_amdgcn_ds_bpermute(adrC, __float_as_uint(w[0][0])));
                    c = fmaxf(c, 1e-37f);
                    cc[q] = c;
                    Ls[q] += __log2f(c);
                    scale = __builtin_amdgcn_rcpf(c);
                }
                // zero-shuffle C->B under pi: pure in-lane packing
#pragma unroll
                for (int kf = 0; kf < 2; ++kf)
#pragma unroll
                    for (int j2 = 0; j2 < 4; ++j2) {
                        int mt = 2 * kf + (j2 >> 1), pr = j2 & 1;
                        float v0 = w[mt][2 * pr], v1 = w[mt][2 * pr + 1];
                        if (k == 7) { v0 *= scale; v1 *= scale; }
                        Bf[q][kf].u[j2] = pk_trunc(v0, v1);
                    }
            }
        }
        if (p == BURNP - 1) {                     // mass baseline S0 per chain
#pragma unroll
            for (int q = 0; q < NQ; ++q) {
                const bool ch0 = (half == 0) && (q == 0) && (s == 0);
                S0v[q] = ch0 ? Ls[q] : (Ls[q] + __log2f(swv[q]) - __log2f(cc[q]));
            }
        }
#pragma unroll
        for (int q = 0; q < NQ; ++q) u[q] = un[q];
    }

    float tot = 0.f;
#pragma unroll
    for (int q = 0; q < NQ; ++q)
        tot += Ls[q] + __log2f(swv[q]) - __log2f(cc[q]) - S0v[q];
    // sum over the 16 streams (s-dim); g-lanes hold duplicates
    tot += __shfl_xor(tot, 1);
    tot += __shfl_xor(tot, 2);
    tot += __shfl_xor(tot, 4);
    tot += __shfl_xor(tot, 8);
    if (lane == 0)
        atomicAdd(out + seq, tot * 0.6931471805599453f);
}

extern "C" void kernel_launch(void* const* d_in, const int* in_sizes, int n_in,
                              void* d_out, int out_size, void* d_ws, size_t ws_size,
                              hipStream_t stream) {
    const float* x  = (const float*)d_in[0];   // [B,T,M] one-hot
    const float* I  = (const float*)d_in[1];   // [1,S]
    const float* A  = (const float*)d_in[2];   // [S,S]
    const float* Bm = (const float*)d_in[3];   // [M,S]
    float* out = (float*)d_out;                // [B,1]
    unsigned char* obs = (unsigned char*)d_ws; // B*T = 2 MB of uint8

    hipMemsetAsync(out, 0, (size_t)out_size * sizeof(float), stream);
    extract_obs<<<(BATCH * T) / 256, 256, 0, stream>>>(x, obs);   // 1 thread/row
    hmm_mfma<<<256, WPB * 64, 0, stream>>>(obs, I, A, Bm, out);   // 1024 waves
}

// Round 12
// 1317.233 us; speedup vs baseline: 1.1234x; 1.1234x over previous
//
#include <hip/hip_runtime.h>

// HMM forward (CgpHmmCell): B=512, T=4096, S=64, M=125.
// Round 12: (1) revert extract to R1's coalesced float4 linear scan (R11's
// early-exit probe lost: wave exits at max over 64 lanes ~ full row, with
// scalar uncoalesced loads). (2) Scan: NQ=2 chains x 16 streams per wave,
// 2048 waves (512 blocks x 4 waves, 256-thr, NO min-waves bound) => ~100
// VGPRs (spill-proof; R7's launch_bounds(512,4) capped at 128 and spilled)
// and 2 waves/SIMD so TLP covers the dependent-MFMA chain latency that has
// pinned every variant at ~1300 cyc/chain-step at 1 wave/SIMD.
// Scan algorithm unchanged from R10 (absmax 0.0): permuted-K contraction
// (zero-shuffle C->B: pi(32kf+8g+2j2+e)=32kf+16(j2>>1)+4g+2(j2&1)+e absorbed
// into Af), 128 chunks/seq x 32 steps, burn 16, mass identity dL = S1-S0,
// chunk-0 exact I*E0 override, one atomicAdd per wave.

#define BATCH 512
#define T 4096
#define S 64
#define M 125
#define CHUNKP 4   // packs per chunk (32 steps)
#define BURNP 2    // burn packs (16 steps)
#define NPACK 6
#define WPB 4
#define NQ 2       // chains per wave

typedef __attribute__((ext_vector_type(8))) short bf16x8;
typedef __attribute__((ext_vector_type(4))) float f32x4;

union BFU { unsigned u[4]; bf16x8 v; };

__device__ __forceinline__ unsigned pk_trunc(float a, float b) {
    return (__float_as_uint(b) & 0xFFFF0000u) | (__float_as_uint(a) >> 16);
}
__device__ __forceinline__ unsigned pk_rne(float a, float b) {
    unsigned ua = __float_as_uint(a); ua += 0x7FFFu + ((ua >> 16) & 1u);
    unsigned ub = __float_as_uint(b); ub += 0x7FFFu + ((ub >> 16) & 1u);
    return (ub & 0xFFFF0000u) | (ua >> 16);
}

// ---------------- Phase 1: one-hot -> byte index (HBM-floor) ----------------
__global__ __launch_bounds__(256) void extract_obs(const float4* __restrict__ x4,
                                                   unsigned char* __restrict__ obs) {
    const long long n4 = (long long)BATCH * T * M / 4;
    long long stride = (long long)gridDim.x * blockDim.x;
    for (long long i = (long long)blockIdx.x * blockDim.x + threadIdx.x; i < n4; i += stride) {
        float4 v = x4[i];
        if (v.x != 0.0f || v.y != 0.0f || v.z != 0.0f || v.w != 0.0f) {
            long long e = i * 4;
            if (v.x != 0.0f) { long long r = (e + 0) / M; obs[r] = (unsigned char)(e + 0 - r * M); }
            if (v.y != 0.0f) { long long r = (e + 1) / M; obs[r] = (unsigned char)(e + 1 - r * M); }
            if (v.z != 0.0f) { long long r = (e + 2) / M; obs[r] = (unsigned char)(e + 2 - r * M); }
            if (v.w != 0.0f) { long long r = (e + 3) / M; obs[r] = (unsigned char)(e + 3 - r * M); }
        }
    }
}

// ---------------- Phase 2: MFMA scan, 2 chains x 16 streams per wave --------
__global__ __launch_bounds__(256) void hmm_mfma(const unsigned char* __restrict__ obs,
                                                const float* __restrict__ Iv,
                                                const float* __restrict__ A,
                                                const float* __restrict__ Bm,
                                                float* __restrict__ out) {
    __shared__ __align__(16) float BmL[M * S];        // 32000 B
    __shared__ __align__(16) float ILds[S];

    const int tid = threadIdx.x, lane = tid & 63;
    const int s = lane & 15, g = lane >> 4;

    for (int i = tid; i < M * S; i += WPB * 64) BmL[i] = Bm[i];
    if (tid < S) ILds[tid] = Iv[tid];
    __syncthreads();

    // A^T fragments under pi: slot (kf,g,j2,e) holds A[p0+e][16mt+s],
    // p0 = 32kf + 16*(j2>>1) + 4g + 2*(j2&1).
    BFU Af[4][2];
#pragma unroll
    for (int mt = 0; mt < 4; ++mt)
#pragma unroll
        for (int kf = 0; kf < 2; ++kf)
#pragma unroll
            for (int j2 = 0; j2 < 4; ++j2) {
                int p0 = 32 * kf + 16 * (j2 >> 1) + 4 * g + 2 * (j2 & 1);
                Af[mt][kf].u[j2] = pk_rne(A[(size_t)p0 * S + mt * 16 + s],
                                          A[(size_t)(p0 + 1) * S + mt * 16 + s]);
            }

    const int W = blockIdx.x * WPB + (tid >> 6);  // 0..2047
    const int seq = W >> 2, quarter = W & 3;      // 4 waves per sequence
    const unsigned long long* orow = (const unsigned long long*)(obs + (size_t)seq * T);
    const int adrC = s << 2;                      // bpermute: pull lane s (g=0)

    int idx0[NQ];
    unsigned long long u[NQ], un[NQ];
    BFU Bf[NQ][2];
    float Ls[NQ], S0v[NQ], cc[NQ], swv[NQ];
#pragma unroll
    for (int q = 0; q < NQ; ++q) {
        int chunk = quarter * 32 + q * 16 + s;    // 0..127: this lane/chain's stream
        idx0[q] = chunk * CHUNKP - BURNP;
        u[q] = orow[idx0[q] < 0 ? 0 : idx0[q]];
        Ls[q] = 0.f; S0v[q] = 0.f; cc[q] = 1.f; swv[q] = 1.f;
#pragma unroll
        for (int kf = 0; kf < 2; ++kf)
#pragma unroll
            for (int j = 0; j < 4; ++j) Bf[q][kf].u[j] = 0x3F803F80u;  // 1.0 seed
    }

    for (int p = 0; p < NPACK; ++p) {
#pragma unroll
        for (int q = 0; q < NQ; ++q) {
            int in_ = idx0[q] + p + 1;
            in_ = in_ < 0 ? 0 : (in_ > T / 8 - 1 ? T / 8 - 1 : in_);
            un[q] = orow[in_];                    // prefetch next pack
        }
        const bool ovp = (quarter == 0) && (p == BURNP);
#pragma unroll
        for (int k = 0; k < 8; ++k) {
#pragma unroll
            for (int q = 0; q < NQ; ++q) {
                const int o = (int)((u[q] >> (8 * k)) & 255ull);
                const float* br = &BmL[o << 6];   // wave-uniform -> broadcast reads
                f32x4 E[4];
#pragma unroll
                for (int mt = 0; mt < 4; ++mt)
                    E[mt] = *(const f32x4*)&br[mt * 16 + g * 4];
                float w[4][4];
#pragma unroll
                for (int mt = 0; mt < 4; ++mt) {
                    f32x4 z = {0.f, 0.f, 0.f, 0.f};
                    z = __builtin_amdgcn_mfma_f32_16x16x32_bf16(Af[mt][0].v, Bf[q][0].v, z, 0, 0, 0);
                    z = __builtin_amdgcn_mfma_f32_16x16x32_bf16(Af[mt][1].v, Bf[q][1].v, z, 0, 0, 0);
#pragma unroll
                    for (int r = 0; r < 4; ++r) w[mt][r] = z[r] * E[mt][r];
                }
                if (ovp && k == 0 && q == 0) {    // exact t=0 init of chunk 0
                    const bool c0 = (s == 0);
#pragma unroll
                    for (int mt = 0; mt < 4; ++mt)
#pragma unroll
                        for (int r = 0; r < 4; ++r)
                            w[mt][r] = c0 ? ILds[mt * 16 + g * 4 + r] * E[mt][r] : w[mt][r];
                }
                float scale = 1.f;
                if (k == 7) {                     // per-pack surrogate rescale
                    float swl = 0.f;
#pragma unroll
                    for (int mt = 0; mt < 4; ++mt)
#pragma unroll
                        for (int r = 0; r < 4; ++r) swl += w[mt][r];
                    swl += __shfl_xor(swl, 16);
                    swl += __shfl_xor(swl, 32);
                    swv[q] = swl;                 // pre-scale mass (boundary/final)
                    float c = __uint_as_float(__builtin_amdgcn_ds_bpermute(adrC, __float_as_uint(w[0][0])));
                    c = fmaxf(c, 1e-37f);
                    cc[q] = c;
                    Ls[q] += __log2f(c);
                    scale = __builtin_amdgcn_rcpf(c);
                }
                // zero-shuffle C->B under pi: pure in-lane packing
#pragma unroll
                for (int kf = 0; kf < 2; ++kf)
#pragma unroll
                    for (int j2 = 0; j2 < 4; ++j2) {
                        int mt = 2 * kf + (j2 >> 1), pr = j2 & 1;
                        float v0 = w[mt][2 * pr], v1 = w[mt][2 * pr + 1];
                        if (k == 7) { v0 *= scale; v1 *= scale; }
                        Bf[q][kf].u[j2] = pk_trunc(v0, v1);
                    }
            }
        }
        if (p == BURNP - 1) {                     // mass baseline S0 per chain
#pragma unroll
            for (int q = 0; q < NQ; ++q) {
                const bool ch0 = (quarter == 0) && (q == 0) && (s == 0);
                S0v[q] = ch0 ? Ls[q] : (Ls[q] + __log2f(swv[q]) - __log2f(cc[q]));
            }
        }
#pragma unroll
        for (int q = 0; q < NQ; ++q) u[q] = un[q];
    }

    float tot = 0.f;
#pragma unroll
    for (int q = 0; q < NQ; ++q)
        tot += Ls[q] + __log2f(swv[q]) - __log2f(cc[q]) - S0v[q];
    // sum over the 16 streams (s-dim); g-lanes hold duplicates
    tot += __shfl_xor(tot, 1);
    tot += __shfl_xor(tot, 2);
    tot += __shfl_xor(tot, 4);
    tot += __shfl_xor(tot, 8);
    if (lane == 0)
        atomicAdd(out + seq, tot * 0.6931471805599453f);
}

extern "C" void kernel_launch(void* const* d_in, const int* in_sizes, int n_in,
                              void* d_out, int out_size, void* d_ws, size_t ws_size,
                              hipStream_t stream) {
    const float* x  = (const float*)d_in[0];   // [B,T,M] one-hot
    const float* I  = (const float*)d_in[1];   // [1,S]
    const float* A  = (const float*)d_in[2];   // [S,S]
    const float* Bm = (const float*)d_in[3];   // [M,S]
    float* out = (float*)d_out;                // [B,1]
    unsigned char* obs = (unsigned char*)d_ws; // B*T = 2 MB of uint8

    hipMemsetAsync(out, 0, (size_t)out_size * sizeof(float), stream);
    extract_obs<<<65536, 256, 0, stream>>>((const float4*)x, obs);
    hmm_mfma<<<512, WPB * 64, 0, stream>>>(obs, I, A, Bm, out);  // 2048 waves, 2 blocks/CU
}

// Round 13
// 1314.319 us; speedup vs baseline: 1.1259x; 1.0022x over previous
//
#include <hip/hip_runtime.h>

// HMM forward (CgpHmmCell): B=512, T=4096, S=64, M=125.
// Round 13: (1) CONSTANT power-of-2 surrogate rescale: any positive scale is
// valid, so scale by 2^56 per pack (per-step mass ~ 2^-7 x 8 steps). Deletes
// the per-pack ds_bpermute/log2f/rcp serial section that gated each pack.
// Mass identity with constants: contribution = log2(swf) - log2(swb) - 4*56
// (chunk 0: log2(swf) - 3*56). wave_sum kept only at boundary+final packs.
// (2) de-chained MFMA: z0,z1 independent (C=0 each), w=(z0+z1)*E — halves
// dependent-MFMA depth per step. (3) extract: 4 contiguous float4/thread,
// 4 independent loads in flight.
// Core unchanged from R10/R12 (absmax 0.0): permuted-K contraction
// (zero-shuffle C->B, pi absorbed into Af), 128 chunks/seq x 32 steps,
// burn 16, chunk-0 exact I*E0 override, 2 chains x 16 streams/wave,
// 2048 waves, one atomicAdd per wave.

#define BATCH 512
#define T 4096
#define S 64
#define M 125
#define CHUNKP 4   // packs per chunk (32 steps)
#define BURNP 2    // burn packs (16 steps)
#define NPACK 6
#define WPB 4
#define NQ 2       // chains per wave
#define RB 56.0f                       // log2 of per-pack constant rescale
#define SCALEF 7.205759403792794e16f   // 2^56

typedef __attribute__((ext_vector_type(8))) short bf16x8;
typedef __attribute__((ext_vector_type(4))) float f32x4;

union BFU { unsigned u[4]; bf16x8 v; };

__device__ __forceinline__ unsigned pk_trunc(float a, float b) {
    return (__float_as_uint(b) & 0xFFFF0000u) | (__float_as_uint(a) >> 16);
}
__device__ __forceinline__ unsigned pk_rne(float a, float b) {
    unsigned ua = __float_as_uint(a); ua += 0x7FFFu + ((ua >> 16) & 1u);
    unsigned ub = __float_as_uint(b); ub += 0x7FFFu + ((ub >> 16) & 1u);
    return (ub & 0xFFFF0000u) | (ua >> 16);
}

// ------- Phase 1: one-hot -> byte index; 4 contiguous float4 per thread ----
__global__ __launch_bounds__(256) void extract_obs(const float4* __restrict__ x4,
                                                   unsigned char* __restrict__ obs) {
    const long long i0 = ((long long)blockIdx.x * 256 + threadIdx.x) * 4;
    float4 v[4];
#pragma unroll
    for (int t = 0; t < 4; ++t) v[t] = x4[i0 + t];   // 4 independent 16B loads
#pragma unroll
    for (int t = 0; t < 4; ++t) {
        float4 vv = v[t];
        if (vv.x != 0.f || vv.y != 0.f || vv.z != 0.f || vv.w != 0.f) {
            long long e = (i0 + t) * 4;
            if (vv.x != 0.f) { long long r = (e + 0) / M; obs[r] = (unsigned char)(e + 0 - r * M); }
            if (vv.y != 0.f) { long long r = (e + 1) / M; obs[r] = (unsigned char)(e + 1 - r * M); }
            if (vv.z != 0.f) { long long r = (e + 2) / M; obs[r] = (unsigned char)(e + 2 - r * M); }
            if (vv.w != 0.f) { long long r = (e + 3) / M; obs[r] = (unsigned char)(e + 3 - r * M); }
        }
    }
}

// ---------------- Phase 2: MFMA scan, 2 chains x 16 streams per wave --------
__global__ __launch_bounds__(256) void hmm_mfma(const unsigned char* __restrict__ obs,
                                                const float* __restrict__ Iv,
                                                const float* __restrict__ A,
                                                const float* __restrict__ Bm,
                                                float* __restrict__ out) {
    __shared__ __align__(16) float BmL[M * S];        // 32000 B
    __shared__ __align__(16) float ILds[S];

    const int tid = threadIdx.x, lane = tid & 63;
    const int s = lane & 15, g = lane >> 4;

    for (int i = tid; i < M * S; i += WPB * 64) BmL[i] = Bm[i];
    if (tid < S) ILds[tid] = Iv[tid];
    __syncthreads();

    // A^T fragments under pi: slot (kf,g,j2,e) holds A[p0+e][16mt+s],
    // p0 = 32kf + 16*(j2>>1) + 4g + 2*(j2&1).
    BFU Af[4][2];
#pragma unroll
    for (int mt = 0; mt < 4; ++mt)
#pragma unroll
        for (int kf = 0; kf < 2; ++kf)
#pragma unroll
            for (int j2 = 0; j2 < 4; ++j2) {
                int p0 = 32 * kf + 16 * (j2 >> 1) + 4 * g + 2 * (j2 & 1);
                Af[mt][kf].u[j2] = pk_rne(A[(size_t)p0 * S + mt * 16 + s],
                                          A[(size_t)(p0 + 1) * S + mt * 16 + s]);
            }

    const int W = blockIdx.x * WPB + (tid >> 6);  // 0..2047
    const int seq = W >> 2, quarter = W & 3;      // 4 waves per sequence
    const unsigned long long* orow = (const unsigned long long*)(obs + (size_t)seq * T);

    int idx0[NQ];
    unsigned long long u[NQ], un[NQ];
    BFU Bf[NQ][2];
    float S0v[NQ], swv[NQ];
#pragma unroll
    for (int q = 0; q < NQ; ++q) {
        int chunk = quarter * 32 + q * 16 + s;    // 0..127: this lane/chain's stream
        idx0[q] = chunk * CHUNKP - BURNP;
        u[q] = orow[idx0[q] < 0 ? 0 : idx0[q]];
        S0v[q] = 0.f; swv[q] = 1.f;
#pragma unroll
        for (int kf = 0; kf < 2; ++kf)
#pragma unroll
            for (int j = 0; j < 4; ++j) Bf[q][kf].u[j] = 0x3F803F80u;  // 1.0 seed
    }

    for (int p = 0; p < NPACK; ++p) {
#pragma unroll
        for (int q = 0; q < NQ; ++q) {
            int in_ = idx0[q] + p + 1;
            in_ = in_ < 0 ? 0 : (in_ > T / 8 - 1 ? T / 8 - 1 : in_);
            un[q] = orow[in_];                    // prefetch next pack
        }
        const bool ovp = (quarter == 0) && (p == BURNP);
        const bool massp = (p == BURNP - 1) || (p == NPACK - 1);
#pragma unroll
        for (int k = 0; k < 8; ++k) {
#pragma unroll
            for (int q = 0; q < NQ; ++q) {
                const int o = (int)((u[q] >> (8 * k)) & 255ull);
                const float* br = &BmL[o << 6];   // wave-uniform -> broadcast reads
                f32x4 E[4];
#pragma unroll
                for (int mt = 0; mt < 4; ++mt)
                    E[mt] = *(const f32x4*)&br[mt * 16 + g * 4];
                float w[4][4];
#pragma unroll
                for (int mt = 0; mt < 4; ++mt) {
                    f32x4 zr = {0.f, 0.f, 0.f, 0.f};
                    f32x4 z0 = __builtin_amdgcn_mfma_f32_16x16x32_bf16(Af[mt][0].v, Bf[q][0].v, zr, 0, 0, 0);
                    f32x4 z1 = __builtin_amdgcn_mfma_f32_16x16x32_bf16(Af[mt][1].v, Bf[q][1].v, zr, 0, 0, 0);
#pragma unroll
                    for (int r = 0; r < 4; ++r) w[mt][r] = (z0[r] + z1[r]) * E[mt][r];
                }
                if (ovp && k == 0 && q == 0) {    // exact t=0 init of chunk 0
                    const bool c0 = (s == 0);
#pragma unroll
                    for (int mt = 0; mt < 4; ++mt)
#pragma unroll
                        for (int r = 0; r < 4; ++r)
                            w[mt][r] = c0 ? ILds[mt * 16 + g * 4 + r] * E[mt][r] : w[mt][r];
                }
                if (k == 7 && massp) {            // mass only where needed
                    float swl = 0.f;
#pragma unroll
                    for (int mt = 0; mt < 4; ++mt)
#pragma unroll
                        for (int r = 0; r < 4; ++r) swl += w[mt][r];
                    swl += __shfl_xor(swl, 16);
                    swl += __shfl_xor(swl, 32);
                    swv[q] = swl;                 // pre-scale mass
                }
                // zero-shuffle C->B under pi; constant 2^56 rescale at k==7
#pragma unroll
                for (int kf = 0; kf < 2; ++kf)
#pragma unroll
                    for (int j2 = 0; j2 < 4; ++j2) {
                        int mt = 2 * kf + (j2 >> 1), pr = j2 & 1;
                        float v0 = w[mt][2 * pr], v1 = w[mt][2 * pr + 1];
                        if (k == 7) { v0 *= SCALEF; v1 *= SCALEF; }
                        Bf[q][kf].u[j2] = pk_trunc(v0, v1);
                    }
            }
        }
        if (p == BURNP - 1) {
            // stored = true*2^RB here; at final, stored = true*2^(5RB)
            // => C = log2(swf) - log2(swb) - 4RB; chunk0: C = log2(swf) - 3RB
#pragma unroll
            for (int q = 0; q < NQ; ++q) {
                const bool ch0 = (quarter == 0) && (q == 0) && (s == 0);
                S0v[q] = ch0 ? (3.0f * RB) : (__log2f(swv[q]) + 4.0f * RB);
            }
        }
#pragma unroll
        for (int q = 0; q < NQ; ++q) u[q] = un[q];
    }

    float tot = 0.f;
#pragma unroll
    for (int q = 0; q < NQ; ++q)
        tot += __log2f(swv[q]) - S0v[q];
    // sum over the 16 streams (s-dim); g-lanes hold duplicates
    tot += __shfl_xor(tot, 1);
    tot += __shfl_xor(tot, 2);
    tot += __shfl_xor(tot, 4);
    tot += __shfl_xor(tot, 8);
    if (lane == 0)
        atomicAdd(out + seq, tot * 0.6931471805599453f);
}

extern "C" void kernel_launch(void* const* d_in, const int* in_sizes, int n_in,
                              void* d_out, int out_size, void* d_ws, size_t ws_size,
                              hipStream_t stream) {
    const float* x  = (const float*)d_in[0];   // [B,T,M] one-hot
    const float* I  = (const float*)d_in[1];   // [1,S]
    const float* A  = (const float*)d_in[2];   // [S,S]
    const float* Bm = (const float*)d_in[3];   // [M,S]
    float* out = (float*)d_out;                // [B,1]
    unsigned char* obs = (unsigned char*)d_ws; // B*T = 2 MB of uint8

    hipMemsetAsync(out, 0, (size_t)out_size * sizeof(float), stream);
    // 65,536,000 float4s / 4 per thread / 256 per block = 64000 blocks exactly
    extract_obs<<<64000, 256, 0, stream>>>((const float4*)x, obs);
    hmm_mfma<<<512, WPB * 64, 0, stream>>>(obs, I, A, Bm, out);  // 2048 waves
}